// Round 1
// baseline (22.159 us; speedup 1.0000x reference)
//
#include <hip/hip_runtime.h>

// Problem constants (from reference setup_inputs): B=4, N=2048, d=3.
#define BATCH 4
#define NPTS  2048
#define BLK   512   // threads per block; 1 block per batch; 4 points/thread

// Symmetric 3x3 index pairs: (0,0),(1,1),(2,2),(0,1),(0,2),(1,2)
__device__ __constant__ int PI6[6] = {0, 1, 2, 0, 0, 1};
__device__ __constant__ int PJ6[6] = {0, 1, 2, 1, 2, 2};

// acc layout (48 floats):
//  [0:3)   sx        sum x
//  [3:6)   sy        sum y
//  [6:12)  sxx       sum x_i x_j (sym6)
//  [12:18) syy       sum y_i y_j (sym6)
//  [18:27) sxy       sum x_i y_j (full 9)
//  [27:33) A         sum Rx Rx^T (sym6)   (row-index pairing: A_jj' = sum_m Rx[j][m]Rx[j'][m])
//  [33:39) Bm        sum Ry Ry^T (sym6)
//  [39:48) C         sum Rx Ry^T (full 9) C[j*3+j'] = sum_m Rx[j][m]Ry[j'][m]
#define NACC 48

__global__ __launch_bounds__(BLK)
void fape_reduce_kernel(const float* __restrict__ x,
                        const float* __restrict__ Rx,
                        const float* __restrict__ y,
                        const float* __restrict__ Ry,
                        float* __restrict__ out)
{
    const int b   = blockIdx.x;
    const int tid = threadIdx.x;

    const float* __restrict__ xb  = x  + (size_t)b * NPTS * 3;
    const float* __restrict__ yb  = y  + (size_t)b * NPTS * 3;
    const float* __restrict__ rxb = Rx + (size_t)b * NPTS * 9;
    const float* __restrict__ ryb = Ry + (size_t)b * NPTS * 9;

    float acc[NACC];
#pragma unroll
    for (int q = 0; q < NACC; ++q) acc[q] = 0.f;

    for (int n = tid; n < NPTS; n += BLK) {
        float xv[3], yv[3], rx[9], ry[9];
#pragma unroll
        for (int i = 0; i < 3; ++i) { xv[i] = xb[n * 3 + i]; yv[i] = yb[n * 3 + i]; }
#pragma unroll
        for (int i = 0; i < 9; ++i) { rx[i] = rxb[n * 9 + i]; ry[i] = ryb[n * 9 + i]; }

#pragma unroll
        for (int i = 0; i < 3; ++i) { acc[0 + i] += xv[i]; acc[3 + i] += yv[i]; }

        // symmetric second moments + frame Gram matrices
#pragma unroll
        for (int p = 0; p < 6; ++p) {
            const int i = PI6[p], j = PJ6[p];
            acc[6  + p] += xv[i] * xv[j];
            acc[12 + p] += yv[i] * yv[j];
            float a = 0.f, bb = 0.f;
#pragma unroll
            for (int m = 0; m < 3; ++m) {
                a  += rx[i * 3 + m] * rx[j * 3 + m];
                bb += ry[i * 3 + m] * ry[j * 3 + m];
            }
            acc[27 + p] += a;
            acc[33 + p] += bb;
        }

        // cross terms (full 3x3)
#pragma unroll
        for (int i = 0; i < 3; ++i) {
#pragma unroll
            for (int j = 0; j < 3; ++j) {
                acc[18 + i * 3 + j] += xv[i] * yv[j];
                float c = 0.f;
#pragma unroll
                for (int m = 0; m < 3; ++m) c += rx[i * 3 + m] * ry[j * 3 + m];
                acc[39 + i * 3 + j] += c;
            }
        }
    }

    // wave-64 shuffle reduction
#pragma unroll
    for (int off = 32; off > 0; off >>= 1) {
#pragma unroll
        for (int q = 0; q < NACC; ++q) acc[q] += __shfl_down(acc[q], off, 64);
    }

    // cross-wave reduction via LDS
    const int NW = BLK / 64;
    __shared__ float red[BLK / 64][NACC];
    const int wave = tid >> 6, lane = tid & 63;
    if (lane == 0) {
#pragma unroll
        for (int q = 0; q < NACC; ++q) red[wave][q] = acc[q];
    }
    __syncthreads();

    __shared__ float fin[NACC];
    if (tid < NACC) {
        float s = 0.f;
#pragma unroll
        for (int w = 0; w < NW; ++w) s += red[w][tid];
        fin[tid] = s;
    }
    __syncthreads();

    if (tid == 0) {
        const double Ninv = 1.0 / (double)NPTS;
        double sx[3], sy[3];
        for (int i = 0; i < 3; ++i) { sx[i] = fin[0 + i]; sy[i] = fin[3 + i]; }

        // centered moments
        double Sx[6], Sy[6], Sxy[9];
        for (int p = 0; p < 6; ++p) {
            const int i = PI6[p], j = PJ6[p];
            Sx[p] = (double)fin[6  + p] - sx[i] * sx[j] * Ninv;
            Sy[p] = (double)fin[12 + p] - sy[i] * sy[j] * Ninv;
        }
        for (int i = 0; i < 3; ++i)
            for (int j = 0; j < 3; ++j)
                Sxy[i * 3 + j] = (double)fin[18 + i * 3 + j] - sx[i] * sy[j] * Ninv;

        double dot = 0.0;
        // symmetric inner products: diag once, off-diag twice
        for (int p = 0; p < 3; ++p) {
            dot += (double)fin[27 + p] * Sx[p] + (double)fin[33 + p] * Sy[p];
        }
        for (int p = 3; p < 6; ++p) {
            dot += 2.0 * ((double)fin[27 + p] * Sx[p] + (double)fin[33 + p] * Sy[p]);
        }
        // cross term
        double cr = 0.0;
        for (int q = 0; q < 9; ++q) cr += (double)fin[39 + q] * Sxy[q];
        dot -= 2.0 * cr;

        const double denom = (double)BATCH * (double)NPTS * (double)NPTS * 3.0;
        atomicAdd(out, (float)(dot / denom));
    }
}

extern "C" void kernel_launch(void* const* d_in, const int* in_sizes, int n_in,
                              void* d_out, int out_size, void* d_ws, size_t ws_size,
                              hipStream_t stream) {
    const float* x  = (const float*)d_in[0];
    const float* Rx = (const float*)d_in[1];
    const float* y  = (const float*)d_in[2];
    const float* Ry = (const float*)d_in[3];
    float* out = (float*)d_out;

    hipMemsetAsync(out, 0, sizeof(float), stream);
    fape_reduce_kernel<<<BATCH, BLK, 0, stream>>>(x, Rx, y, Ry, out);
}